// Round 1
// baseline (203.399 us; speedup 1.0000x reference)
//
#include <hip/hip_runtime.h>

#define ORDER 24

// out[n] = sum_{i,j,k} sin(2pi*x_n*i) sin(2pi*y_n*j) sin(2pi*z_n*k) C[i,j,k]
// Index 0 of each dimension is sin(0)=0 -> skipped entirely.
// C accessed only at wave-uniform addresses -> scalar (s_load) path.
__global__ __launch_bounds__(256) void fourier_surface_kernel(
    const float* __restrict__ xyz,
    const float* __restrict__ coeffs,
    float* __restrict__ out,
    int n)
{
    const int tid = blockIdx.x * blockDim.x + threadIdx.x;
    if (tid >= n) return;

    const float TWO_PI = 6.28318530717958647692f;
    const float x = xyz[3 * tid + 0];
    const float y = xyz[3 * tid + 1];
    const float z = xyz[3 * tid + 2];

    float s1x, c1x, s1y, c1y, s1z, c1z;
    __sincosf(TWO_PI * x, &s1x, &c1x);
    __sincosf(TWO_PI * y, &s1y, &c1y);
    __sincosf(TWO_PI * z, &s1z, &c1z);

    // Chebyshev recurrence: sin(k*t) = 2cos(t)*sin((k-1)t) - sin((k-2)t)
    // sy_/sz_ are only ever indexed with compile-time constants (unrolled
    // loops) so they live in VGPRs, not scratch.
    float sy_[ORDER], sz_[ORDER];
    sy_[0] = 0.0f; sy_[1] = s1y;
    sz_[0] = 0.0f; sz_[1] = s1z;
    const float c2y = 2.0f * c1y;
    const float c2z = 2.0f * c1z;
#pragma unroll
    for (int k = 2; k < ORDER; ++k) sy_[k] = fmaf(c2y, sy_[k - 1], -sy_[k - 2]);
#pragma unroll
    for (int k = 2; k < ORDER; ++k) sz_[k] = fmaf(c2z, sz_[k - 1], -sz_[k - 2]);

    // sx handled as a loop-carried recurrence across the rolled i-loop:
    // no runtime-indexed register array (rule #20).
    const float c2x = 2.0f * c1x;
    float sx_prev = 0.0f;   // sin(0)
    float sx_cur  = s1x;    // sin(2pi x)

    float acc = 0.0f;

#pragma unroll 1            // keep i rolled: body ~550 VALU ops, I$-friendly
    for (int i = 1; i < ORDER; ++i) {
        const float* __restrict__ Ci = coeffs + i * (ORDER * ORDER);
        float b = 0.0f;
#pragma unroll              // j,k fully unrolled: 23 independent 23-FMA chains
        for (int j = 1; j < ORDER; ++j) {
            const float* __restrict__ Cij = Ci + j * ORDER;
            float a = 0.0f;
#pragma unroll
            for (int k = 1; k < ORDER; ++k) {
                a = fmaf(sz_[k], Cij[k], a);   // Cij[k] is wave-uniform -> SGPR
            }
            b = fmaf(sy_[j], a, b);
        }
        acc = fmaf(sx_cur, b, acc);
        const float sx_next = fmaf(c2x, sx_cur, -sx_prev);
        sx_prev = sx_cur;
        sx_cur  = sx_next;
    }

    out[tid] = acc;
}

extern "C" void kernel_launch(void* const* d_in, const int* in_sizes, int n_in,
                              void* d_out, int out_size, void* d_ws, size_t ws_size,
                              hipStream_t stream) {
    const float* xyz    = (const float*)d_in[0];   // (N,3) fp32
    const float* coeffs = (const float*)d_in[1];   // (24^3,) fp32
    float* out = (float*)d_out;                    // (N,) fp32

    const int n = in_sizes[0] / 3;
    const int block = 256;
    const int grid = (n + block - 1) / block;
    fourier_surface_kernel<<<grid, block, 0, stream>>>(xyz, coeffs, out, n);
}

// Round 2
// 65.737 us; speedup vs baseline: 3.0941x; 3.0941x over previous
//
#include <hip/hip_runtime.h>
#include <hip/hip_bf16.h>

#define ORDER 24
#define TWO_PI 6.28318530717958647692f

typedef __attribute__((ext_vector_type(8))) short bf16x8;   // 8 bf16 = 4 VGPRs
typedef __attribute__((ext_vector_type(4))) float f32x4;    // MFMA acc

__device__ __forceinline__ short f2bf(float f) {
    __hip_bfloat16 h = __float2bfloat16(f);
    return __builtin_bit_cast(short, h);
}

// out[n] = sum_i sx_i(n) * T[n,i],  T[n,i] = sum_{j,k} sy_j(n) sz_k(n) C[i,j,k]
// GEMM: M=points(16/tile), N=i(24, 2 n-tiles of 16), K=(j,k) padded to 24*32.
// K-step s == j; within a step, lane k-slot = 8*(lane>>4)+e  (g==3 -> k>=24 -> A=0).
// A-frags built in registers (static indices only); B (C as bf16) in LDS frag-order.
__global__ __launch_bounds__(256) void fourier_mfma(
    const float* __restrict__ xyz,
    const float* __restrict__ coeffs,
    float* __restrict__ out)
{
    // 48 frags (s=0..23 x ntile t=0,1) x 48 lane-slots x 8 bf16 = 36864 B
    __shared__ __align__(16) unsigned short Bl[48 * 48 * 8];

    const int tid  = threadIdx.x;
    const int wave = tid >> 6;
    const int lane = tid & 63;
    const int g    = lane >> 4;   // k-group
    const int c    = lane & 15;   // A-row / B-col within fragment

    // ---- cooperative fill of B frags: slot (f=2s+t, sl): value[e] = bf16(C[i][s][8*gg+e]) ----
    for (int pass = 0; pass < 9; ++pass) {
        int chunk = pass * 256 + tid;       // 0..2303, exact
        int f  = chunk / 48, sl = chunk % 48;
        int s  = f >> 1,  tt = f & 1;
        int gg = sl >> 4, cc = sl & 15;
        int i  = 16 * tt + cc;
        bf16x8 v;
        if (i < 24) {
            const float* src = coeffs + i * 576 + s * 24 + gg * 8;
#pragma unroll
            for (int e = 0; e < 8; ++e) v[e] = f2bf(src[e]);
        } else {
#pragma unroll
            for (int e = 0; e < 8; ++e) v[e] = 0;
        }
        ((bf16x8*)Bl)[chunk] = v;
    }

    // ---- per-wave setup: 64 points per wave (4 M-tiles of 16) ----
    const int gid = blockIdx.x * 4 + wave;
    const int p0  = gid * 64;

    float syp[4], syc[4], c2y[4];   // sin(j*thy) recurrence state per M-tile
    float sz8[4][8];                // sin((8g+e)*thz) per M-tile, static-indexed
    const float kmask = (g < 3) ? 1.0f : 0.0f;   // k>=24 pad -> zero A slots

#pragma unroll
    for (int m = 0; m < 4; ++m) {
        int p = p0 + 16 * m + c;    // A-frag row c -> point 16m+c
        float y = xyz[3 * p + 1];
        float z = xyz[3 * p + 2];
        float sy1, cy1; __sincosf(TWO_PI * y, &sy1, &cy1);
        syp[m] = 0.0f; syc[m] = sy1; c2y[m] = 2.0f * cy1;
        float sz1, cz1; __sincosf(TWO_PI * z, &sz1, &cz1);
        float sb, cb;   __sincosf(TWO_PI * (float)(8 * g) * z, &sb, &cb);
        float c2z = 2.0f * cz1;
        sz8[m][0] = sb * kmask;                       // sin(8g*thz)
        sz8[m][1] = fmaf(sb, cz1, cb * sz1) * kmask;  // sin((8g+1)*thz)
#pragma unroll
        for (int e = 2; e < 8; ++e)
            sz8[m][e] = fmaf(c2z, sz8[m][e - 1], -sz8[m][e - 2]);
    }

    f32x4 acc[4][2];
#pragma unroll
    for (int m = 0; m < 4; ++m) {
        acc[m][0] = f32x4{0.f, 0.f, 0.f, 0.f};
        acc[m][1] = f32x4{0.f, 0.f, 0.f, 0.f};
    }

    __syncthreads();

    const int bslot = (lane < 48) ? lane : 47;  // g==3 lanes: broadcast slot47 (finite; A=0 anyway)
    const bf16x8* Bf = (const bf16x8*)Bl;

    // ---- main loop: s = j (j=0 contributes 0, skipped) ----
#pragma unroll
    for (int s = 1; s < 24; ++s) {
        bf16x8 b0 = Bf[(2 * s + 0) * 48 + bslot];
        bf16x8 b1 = Bf[(2 * s + 1) * 48 + bslot];
#pragma unroll
        for (int m = 0; m < 4; ++m) {
            bf16x8 a;
#pragma unroll
            for (int e = 0; e < 8; ++e) a[e] = f2bf(syc[m] * sz8[m][e]);
            acc[m][0] = __builtin_amdgcn_mfma_f32_16x16x32_bf16(a, b0, acc[m][0], 0, 0, 0);
            acc[m][1] = __builtin_amdgcn_mfma_f32_16x16x32_bf16(a, b1, acc[m][1], 0, 0, 0);
            float nxt = fmaf(c2y[m], syc[m], -syp[m]);
            syp[m] = syc[m]; syc[m] = nxt;
        }
    }

    __syncthreads();   // all waves done reading B -> reuse LDS as T buffer

    // ---- scatter T[point][i]: per-wave region, row stride 36 floats (i up to 31 fits) ----
    float* T = (float*)Bl + wave * (64 * 36);
#pragma unroll
    for (int m = 0; m < 4; ++m)
#pragma unroll
        for (int t = 0; t < 2; ++t)
#pragma unroll
            for (int r = 0; r < 4; ++r) {
                int pr = 16 * m + 4 * g + r;   // D row = (lane>>4)*4 + reg (m89-verified)
                int ii = 16 * t + c;           // D col
                T[pr * 36 + ii] = acc[m][t][r];
            }

    __syncthreads();

    // ---- epilogue: out[p] = sum_{i=1..23} sin(2pi x i) * T[p][i] ----
    {
        int p = p0 + lane;
        float x = xyz[3 * p];
        float sx1, cx1; __sincosf(TWO_PI * x, &sx1, &cx1);
        const float* Tr = T + lane * 36;
        float res = 0.0f;
        float sp = 0.0f, scur = sx1;
        const float c2x = 2.0f * cx1;
#pragma unroll
        for (int i = 1; i < 24; ++i) {
            res = fmaf(scur, Tr[i], res);
            float nx = fmaf(c2x, scur, -sp);
            sp = scur; scur = nx;
        }
        out[p] = res;
    }
}

extern "C" void kernel_launch(void* const* d_in, const int* in_sizes, int n_in,
                              void* d_out, int out_size, void* d_ws, size_t ws_size,
                              hipStream_t stream) {
    const float* xyz    = (const float*)d_in[0];
    const float* coeffs = (const float*)d_in[1];
    float* out = (float*)d_out;

    const int n = in_sizes[0] / 3;          // 524288 = 2048 blocks * 4 waves * 64 pts
    const int grid = n / 256;
    fourier_mfma<<<grid, 256, 0, stream>>>(xyz, coeffs, out);
}

// Round 3
// 35.732 us; speedup vs baseline: 5.6924x; 1.8397x over previous
//
#include <hip/hip_runtime.h>

typedef _Float16 f16x2 __attribute__((ext_vector_type(2)));
typedef _Float16 f16x8 __attribute__((ext_vector_type(8)));
typedef float    f32x4 __attribute__((ext_vector_type(4)));

// out[n] = sum_i sx_i(n) * T[n,i],  T[n,i] = sum_{j,k} sy_j(n) sz_k(n) C[i,j,k]
// GEMM (fp16 MFMA): M=points, N=i (2 tiles of 16), K=(j,k) with K-step s == j,
// lane k-slot = 8*(lane>>4)+e, k>=24 padded to zero on the A side.
// Native v_sin/v_cos take REVOLUTIONS: sin(2pi*x) = __builtin_amdgcn_sinf(x).
__global__ __launch_bounds__(256, 4) void fourier_mfma(
    const float* __restrict__ xyz,
    const float* __restrict__ coeffs,
    float* __restrict__ out)
{
    // region 0: B frags (48 frags x 48 slots x 16B = 36864 B)
    // region 1 (after barrier, reuse): T[4 waves][64 rows][37 floats] = 37888 B
    __shared__ __align__(16) unsigned short Bl[18944];

    const int tid  = threadIdx.x;
    const int wave = tid >> 6;
    const int lane = tid & 63;
    const int g    = lane >> 4;   // k-group
    const int c    = lane & 15;   // A-row / B-col within fragment

    // ---- cooperative B fill: frag f=2s+t, slot sl=16gg+cc: v[e] = f16(C[i][s][8gg+e]) ----
    for (int pass = 0; pass < 9; ++pass) {
        int chunk = pass * 256 + tid;       // 0..2303 exact
        int f  = chunk / 48, sl = chunk % 48;
        int s  = f >> 1,  tt = f & 1;
        int gg = sl >> 4, cc = sl & 15;
        int i  = 16 * tt + cc;
        f16x8 v;
        if (i < 24) {
            const float* src = coeffs + i * 576 + s * 24 + gg * 8;
#pragma unroll
            for (int e = 0; e < 8; ++e) v[e] = (_Float16)src[e];
        } else {
#pragma unroll
            for (int e = 0; e < 8; ++e) v[e] = (_Float16)0.f;
        }
        ((f16x8*)Bl)[chunk] = v;
    }

    // ---- per-wave setup: 64 points (4 M-tiles of 16) ----
    const int gid = blockIdx.x * 4 + wave;
    const int p0  = gid * 64;

    float syp[4], syc[4], c2y[4];   // fp32 sin(j*thy) recurrence per M-tile
    f16x2 sz2[4][4];                // f16 packed sin((8g+e)*thz), e pairs
    const float kmask = (g < 3) ? 1.0f : 0.0f;   // k>=24 pad

#pragma unroll
    for (int m = 0; m < 4; ++m) {
        int p = p0 + 16 * m + c;
        float y = xyz[3 * p + 1];
        float z = xyz[3 * p + 2];
        float sy1 = __builtin_amdgcn_sinf(y);
        float cy1 = __builtin_amdgcn_cosf(y);
        syp[m] = 0.0f; syc[m] = sy1; c2y[m] = 2.0f * cy1;
        float sz1 = __builtin_amdgcn_sinf(z);
        float cz1 = __builtin_amdgcn_cosf(z);
        float w   = __builtin_amdgcn_fractf((float)(8 * g) * z);
        float sb  = __builtin_amdgcn_sinf(w) * kmask;    // sin(8g*thz), masked
        float cb  = __builtin_amdgcn_cosf(w);
        float c2z = 2.0f * cz1;
        float szf[8];
        szf[0] = sb;
        szf[1] = fmaf(sb, cz1, cb * sz1 * kmask);        // sin((8g+1)*thz), masked
#pragma unroll
        for (int e = 2; e < 8; ++e) szf[e] = fmaf(c2z, szf[e - 1], -szf[e - 2]);
#pragma unroll
        for (int q = 0; q < 4; ++q)
            sz2[m][q] = f16x2{(_Float16)szf[2 * q], (_Float16)szf[2 * q + 1]};
    }

    f32x4 acc[4][2] = {};

    __syncthreads();

    const int bslot = (lane < 48) ? lane : 47;  // g==3: broadcast (finite; A=0 anyway)
    const f16x8* Bf = (const f16x8*)Bl;

    // ---- main loop: s = j (j=0 contributes 0, skipped) ----
#pragma unroll
    for (int s = 1; s < 24; ++s) {
        f16x8 b0 = Bf[(2 * s + 0) * 48 + bslot];
        f16x8 b1 = Bf[(2 * s + 1) * 48 + bslot];
#pragma unroll
        for (int m = 0; m < 4; ++m) {
            _Float16 hy = (_Float16)syc[m];
            f16x2 hy2 = {hy, hy};
            f16x8 a;
#pragma unroll
            for (int q = 0; q < 4; ++q) {          // 4x v_pk_mul_f16
                f16x2 pr = hy2 * sz2[m][q];
                a[2 * q]     = pr[0];
                a[2 * q + 1] = pr[1];
            }
            acc[m][0] = __builtin_amdgcn_mfma_f32_16x16x32_f16(a, b0, acc[m][0], 0, 0, 0);
            acc[m][1] = __builtin_amdgcn_mfma_f32_16x16x32_f16(a, b1, acc[m][1], 0, 0, 0);
            float nxt = fmaf(c2y[m], syc[m], -syp[m]);
            syp[m] = syc[m]; syc[m] = nxt;
        }
    }

    __syncthreads();   // all waves done reading B -> reuse LDS as T

    // ---- scatter T[point][i], row stride 37 floats (conflict-free epilogue reads) ----
    float* T = (float*)Bl + wave * (64 * 37);
#pragma unroll
    for (int m = 0; m < 4; ++m)
#pragma unroll
        for (int t = 0; t < 2; ++t)
#pragma unroll
            for (int r = 0; r < 4; ++r) {
                int pr = 16 * m + 4 * g + r;   // D row = (lane>>4)*4 + reg
                int ii = 16 * t + c;           // D col
                T[pr * 37 + ii] = acc[m][t][r];
            }

    __syncthreads();

    // ---- epilogue: out[p] = sum_{i=1..23} sin(2pi*i*x) * T[p][i] ----
    {
        int p = p0 + lane;
        float x = xyz[3 * p];
        float sx1 = __builtin_amdgcn_sinf(x);
        float cx1 = __builtin_amdgcn_cosf(x);
        const float* Tr = T + lane * 37;
        float res = 0.0f;
        float sp = 0.0f, scur = sx1;
        const float c2x = 2.0f * cx1;
#pragma unroll
        for (int i = 1; i < 24; ++i) {
            res = fmaf(scur, Tr[i], res);
            float nx = fmaf(c2x, scur, -sp);
            sp = scur; scur = nx;
        }
        out[p] = res;
    }
}

extern "C" void kernel_launch(void* const* d_in, const int* in_sizes, int n_in,
                              void* d_out, int out_size, void* d_ws, size_t ws_size,
                              hipStream_t stream) {
    const float* xyz    = (const float*)d_in[0];
    const float* coeffs = (const float*)d_in[1];
    float* out = (float*)d_out;

    const int n = in_sizes[0] / 3;          // 524288 = 2048 blocks * 4 waves * 64 pts
    const int grid = n / 256;
    fourier_mfma<<<grid, 256, 0, stream>>>(xyz, coeffs, out);
}

// Round 5
// 34.781 us; speedup vs baseline: 5.8479x; 1.0273x over previous
//
#include <hip/hip_runtime.h>

typedef _Float16 f16x2 __attribute__((ext_vector_type(2)));
typedef _Float16 f16x8 __attribute__((ext_vector_type(8)));
typedef __fp16   fp16v2 __attribute__((ext_vector_type(2)));   // cvt_pkrtz return type
typedef float    f32x4 __attribute__((ext_vector_type(4)));

#define TSTRIDE 21   // T row stride in 32-bit words (coprime with 32 banks)

// ---- prep: C (f32) -> frag-ordered f16 B in workspace (once per launch) ----
// chunk = (2s+t)*48 + (16gg+cc): v[e] = f16(C[16t+cc][s][8gg+e]); i>=24 -> 0
__global__ __launch_bounds__(256) void prep_B(const float* __restrict__ coeffs,
                                              f16x8* __restrict__ wsB)
{
    int chunk = blockIdx.x * 256 + threadIdx.x;   // 0..2303 (grid 9 x 256 exact)
    int f  = chunk / 48, sl = chunk % 48;
    int s  = f >> 1,  tt = f & 1;
    int gg = sl >> 4, cc = sl & 15;
    int i  = 16 * tt + cc;
    f16x8 v;
    if (i < 24) {
        const float* src = coeffs + i * 576 + s * 24 + gg * 8;
#pragma unroll
        for (int e = 0; e < 8; ++e) v[e] = (_Float16)src[e];
    } else {
#pragma unroll
        for (int e = 0; e < 8; ++e) v[e] = (_Float16)0.f;
    }
    wsB[chunk] = v;
}

// ---- main: GEMM (fp16 MFMA) + in-register A build + f16 T epilogue ----
// out[n] = sum_i sx_i * T[n,i],  T[n,i] = sum_{j,k} sy_j sz_k C[i,j,k]
// M=points (2 tiles of 16 per wave), N=i (2 tiles), K-step s == j, k padded to 32.
__global__ __launch_bounds__(512, 8) void fourier_main(
    const float* __restrict__ xyz,
    const f16x8* __restrict__ wsB,
    float* __restrict__ out)
{
    __shared__ __align__(16) f16x8 Bl[2304];   // 36864 B; reused as T after loop

    const int tid  = threadIdx.x;
    const int wave = tid >> 6;
    const int lane = tid & 63;
    const int g    = lane >> 4;   // k-group
    const int c    = lane & 15;   // A-row / B-col within fragment

    // stage B from ws: 2304 chunks, 512 threads, 4.5 passes (coalesced 16B)
#pragma unroll
    for (int pass = 0; pass < 4; ++pass)
        Bl[pass * 512 + tid] = wsB[pass * 512 + tid];
    if (tid < 256) Bl[2048 + tid] = wsB[2048 + tid];

    const int p0 = (blockIdx.x * 8 + wave) * 32;   // 32 points per wave

    // per-wave setup (native v_sin/v_cos take revolutions: arg is x itself)
    float syp[2], syc[2], c2y[2];
    f16x2 sz2[2][4];
    const float kmask = (g < 3) ? 1.0f : 0.0f;     // k>=24 pad -> zero A

#pragma unroll
    for (int m = 0; m < 2; ++m) {
        int p = p0 + 16 * m + c;
        float y = xyz[3 * p + 1];
        float z = xyz[3 * p + 2];
        float sy1 = __builtin_amdgcn_sinf(y);
        float cy1 = __builtin_amdgcn_cosf(y);
        syp[m] = 0.f; syc[m] = sy1; c2y[m] = 2.f * cy1;
        float sz1 = __builtin_amdgcn_sinf(z);
        float cz1 = __builtin_amdgcn_cosf(z);
        float wv  = __builtin_amdgcn_fractf((float)(8 * g) * z);
        float sb  = __builtin_amdgcn_sinf(wv) * kmask;   // sin(8g*thz), masked
        float cb  = __builtin_amdgcn_cosf(wv);
        float c2z = 2.f * cz1;
        float szf[8];
        szf[0] = sb;
        szf[1] = fmaf(sb, cz1, cb * sz1 * kmask);
#pragma unroll
        for (int e = 2; e < 8; ++e) szf[e] = fmaf(c2z, szf[e - 1], -szf[e - 2]);
#pragma unroll
        for (int q = 0; q < 4; ++q)
            sz2[m][q] = f16x2{(_Float16)szf[2 * q], (_Float16)szf[2 * q + 1]};
    }

    f32x4 acc[2][2] = {};

    __syncthreads();

    const int bslot = (lane < 48) ? lane : 47;  // g==3: A=0, B value irrelevant
    // main loop: s = j (j=0 contributes 0, skipped)
#pragma unroll
    for (int s = 1; s < 24; ++s) {
        f16x8 b0 = Bl[(2 * s + 0) * 48 + bslot];
        f16x8 b1 = Bl[(2 * s + 1) * 48 + bslot];
#pragma unroll
        for (int m = 0; m < 2; ++m) {
            _Float16 hy = (_Float16)syc[m];
            f16x2 hy2 = {hy, hy};
            f16x8 a;
#pragma unroll
            for (int q = 0; q < 4; ++q) {
                f16x2 pr = hy2 * sz2[m][q];
                a[2 * q]     = pr[0];
                a[2 * q + 1] = pr[1];
            }
            acc[m][0] = __builtin_amdgcn_mfma_f32_16x16x32_f16(a, b0, acc[m][0], 0, 0, 0);
            acc[m][1] = __builtin_amdgcn_mfma_f32_16x16x32_f16(a, b1, acc[m][1], 0, 0, 0);
            float nxt = fmaf(c2y[m], syc[m], -syp[m]);
            syp[m] = syc[m]; syc[m] = nxt;
        }
    }

    __syncthreads();   // all waves done reading B -> reuse LDS as T (f16-packed)

    // scatter T: word (lr*TSTRIDE + c) = pk(acc[.][t=0][r], acc[.][t=1][r])
    // word w of a row holds cols i=w (lo) and i=w+16 (hi)
    unsigned int* Tw = (unsigned int*)Bl + wave * (32 * TSTRIDE);
#pragma unroll
    for (int m = 0; m < 2; ++m)
#pragma unroll
        for (int r = 0; r < 4; ++r) {
            int lr = 16 * m + 4 * g + r;          // D row = (lane>>4)*4 + reg
            fp16v2 pk = __builtin_amdgcn_cvt_pkrtz(acc[m][0][r], acc[m][1][r]);
            Tw[lr * TSTRIDE + c] = __builtin_bit_cast(unsigned int, pk);
        }

    __syncthreads();

    // epilogue: row lr = lane&31 (upper half-wave redundant, broadcast reads)
    {
        int lr = lane & 31;
        int p  = p0 + lr;
        float x   = xyz[3 * p];
        float s1  = __builtin_amdgcn_sinf(x);
        float c1  = __builtin_amdgcn_cosf(x);
        float f16x_ = __builtin_amdgcn_fractf(16.f * x);   // 16x exact in f32
        float s16 = __builtin_amdgcn_sinf(f16x_);
        float c16 = __builtin_amdgcn_cosf(f16x_);
        const float c2x = 2.f * c1;
        float sA0 = 0.f,  sA1 = s1;                         // sin(2pi*w*x)
        float sB0 = s16,  sB1 = fmaf(s16, c1, c16 * s1);    // sin(2pi*(16+w)*x)
        float res = 0.f;
        const unsigned int* Tr = Tw + lr * TSTRIDE;
#pragma unroll
        for (int w = 0; w < 16; ++w) {
            f16x2 h = __builtin_bit_cast(f16x2, Tr[w]);
            res = fmaf(sA0, (float)h[0], res);
            res = fmaf(sB0, (float)h[1], res);   // i>=24: T==0
            float nA = fmaf(c2x, sA1, -sA0);
            float nB = fmaf(c2x, sB1, -sB0);
            sA0 = sA1; sA1 = nA;
            sB0 = sB1; sB1 = nB;
        }
        if (lane < 32) out[p] = res;
    }
}

extern "C" void kernel_launch(void* const* d_in, const int* in_sizes, int n_in,
                              void* d_out, int out_size, void* d_ws, size_t ws_size,
                              hipStream_t stream) {
    const float* xyz    = (const float*)d_in[0];
    const float* coeffs = (const float*)d_in[1];
    float* out = (float*)d_out;
    f16x8* wsB = (f16x8*)d_ws;                 // needs 36864 B

    prep_B<<<9, 256, 0, stream>>>(coeffs, wsB);

    const int n = in_sizes[0] / 3;             // 524288 = 2048 blocks * 8 waves * 32
    const int grid = n / 256;
    fourier_main<<<grid, 512, 0, stream>>>(xyz, wsB, out);
}

// Round 6
// 31.446 us; speedup vs baseline: 6.4682x; 1.1061x over previous
//
#include <hip/hip_runtime.h>

typedef _Float16 f16x2 __attribute__((ext_vector_type(2)));
typedef _Float16 f16x8 __attribute__((ext_vector_type(8)));
typedef __fp16   fp16v2 __attribute__((ext_vector_type(2)));   // cvt_pkrtz return type
typedef float    f32x4 __attribute__((ext_vector_type(4)));
typedef unsigned int u32x4 __attribute__((ext_vector_type(4)));

#define TSTRIDE 17   // T row stride in 32-bit words (odd -> 2-way-free epilogue reads)

__device__ __forceinline__ f16x2 pk2(float lo, float hi) {
    fp16v2 p = __builtin_amdgcn_cvt_pkrtz(lo, hi);
    return __builtin_bit_cast(f16x2, p);
}

// ---- prep: C (f32) -> frag-ordered f16 B in workspace (once per launch) ----
// chunk = (2s+t)*48 + (16gg+cc): v[e] = f16(C[16t+cc][s][8gg+e]); i>=24 -> 0
__global__ __launch_bounds__(256) void prep_B(const float* __restrict__ coeffs,
                                              f16x8* __restrict__ wsB)
{
    int chunk = blockIdx.x * 256 + threadIdx.x;   // 0..2303 (grid 9 x 256 exact)
    int f  = chunk / 48, sl = chunk % 48;
    int s  = f >> 1,  tt = f & 1;
    int gg = sl >> 4, cc = sl & 15;
    int i  = 16 * tt + cc;
    f16x8 v;
    if (i < 24) {
        const float* src = coeffs + i * 576 + s * 24 + gg * 8;
#pragma unroll
        for (int e = 0; e < 8; ++e) v[e] = (_Float16)src[e];
    } else {
#pragma unroll
        for (int e = 0; e < 8; ++e) v[e] = (_Float16)0.f;
    }
    wsB[chunk] = v;
}

// ---- main: out[n] = sum_i sx_i * T[n,i], T[n,i] = sum_{j,k} sy_j sz_k C[i,j,k]
// fp16 MFMA 16x16x32: M=points (4 tiles of 16 / wave), N=i (2 tiles), K-step s == j.
// Native v_sin/v_cos take REVOLUTIONS: sin(2pi*x) = __builtin_amdgcn_sinf(x).
__global__ __launch_bounds__(512, 4) void fourier_main(
    const float* __restrict__ xyz,
    const f16x8* __restrict__ wsB,
    float* __restrict__ out)
{
    __shared__ __align__(16) f16x8 Bl[2304];   // 36864 B; T overlay 8*64*17*4=34816 B

    const int tid  = threadIdx.x;
    const int wave = tid >> 6;
    const int lane = tid & 63;
    const int g    = lane >> 4;   // k-group
    const int c    = lane & 15;   // A-row / B-col within fragment

    // stage B from ws (coalesced 16B copies)
#pragma unroll
    for (int pass = 0; pass < 4; ++pass)
        Bl[pass * 512 + tid] = wsB[pass * 512 + tid];
    if (tid < 256) Bl[2048 + tid] = wsB[2048 + tid];

    const int p0 = (blockIdx.x * 8 + wave) * 64;   // 64 points per wave

    // preload epilogue x NOW (hide HBM latency behind setup + main loop)
    const float xv = xyz[3 * (p0 + lane)];

    float syp[4], syc[4], c2y[4];   // fp32 sin(j*thy) recurrence per M-tile
    f16x2 sz2[4][4];                // packed f16 sin((8g+e)*thz)
    const float kmask = (g < 3) ? 1.0f : 0.0f;   // k>=24 pad -> zero A

#pragma unroll
    for (int m = 0; m < 4; ++m) {
        int p = p0 + 16 * m + c;
        float y = xyz[3 * p + 1];
        float z = xyz[3 * p + 2];
        float sy1 = __builtin_amdgcn_sinf(y);
        float cy1 = __builtin_amdgcn_cosf(y);
        syp[m] = 0.f; syc[m] = sy1; c2y[m] = 2.f * cy1;
        float sz1 = __builtin_amdgcn_sinf(z);
        float cz1 = __builtin_amdgcn_cosf(z);
        float wv  = __builtin_amdgcn_fractf((float)(8 * g) * z);
        float sb  = __builtin_amdgcn_sinf(wv) * kmask;   // sin(8g*thz), masked
        float cb  = __builtin_amdgcn_cosf(wv);
        float c2z = 2.f * cz1;
        float szf[8];
        szf[0] = sb;
        szf[1] = fmaf(sb, cz1, cb * sz1 * kmask);
#pragma unroll
        for (int e = 2; e < 8; ++e) szf[e] = fmaf(c2z, szf[e - 1], -szf[e - 2]);
#pragma unroll
        for (int q = 0; q < 4; ++q) sz2[m][q] = pk2(szf[2 * q], szf[2 * q + 1]);
    }

    f32x4 acc[4][2] = {};

    __syncthreads();

    const int bslot = (lane < 48) ? lane : 47;  // g==3: A=0, B value irrelevant
    // main loop: s = j (j=0 contributes 0, skipped); ds offsets fold to immediates
#pragma unroll
    for (int s = 1; s < 24; ++s) {
        f16x8 b0 = Bl[(2 * s + 0) * 48 + bslot];
        f16x8 b1 = Bl[(2 * s + 1) * 48 + bslot];
#pragma unroll
        for (int m = 0; m < 4; ++m) {
            f16x2 hy2 = pk2(syc[m], syc[m]);       // 1 instr: cvt + broadcast
            u32x4 aw;
#pragma unroll
            for (int q = 0; q < 4; ++q) {          // 4x v_pk_mul_f16
                f16x2 pr = hy2 * sz2[m][q];
                aw[q] = __builtin_bit_cast(unsigned int, pr);
            }
            f16x8 a = __builtin_bit_cast(f16x8, aw);
            acc[m][0] = __builtin_amdgcn_mfma_f32_16x16x32_f16(a, b0, acc[m][0], 0, 0, 0);
            acc[m][1] = __builtin_amdgcn_mfma_f32_16x16x32_f16(a, b1, acc[m][1], 0, 0, 0);
            float nxt = fmaf(c2y[m], syc[m], -syp[m]);
            syp[m] = syc[m]; syc[m] = nxt;
        }
    }

    __syncthreads();   // B no longer needed -> reuse LDS as packed-f16 T

    // scatter T: word (lr*TSTRIDE + c) = pk(acc[t=0][r], acc[t=1][r])
    // word w of a row holds i=w (lo) and i=16+w (hi; i>=24 slots are zero)
    unsigned int* Tw = (unsigned int*)Bl + wave * (64 * TSTRIDE);
#pragma unroll
    for (int m = 0; m < 4; ++m)
#pragma unroll
        for (int r = 0; r < 4; ++r) {
            int lr = 16 * m + 4 * g + r;          // D row = (lane>>4)*4 + reg
            fp16v2 pk = __builtin_amdgcn_cvt_pkrtz(acc[m][0][r], acc[m][1][r]);
            Tw[lr * TSTRIDE + c] = __builtin_bit_cast(unsigned int, pk);
        }

    __syncthreads();

    // epilogue: lane owns row lane (64 rows/wave), fully coalesced store
    {
        int p = p0 + lane;
        float s1  = __builtin_amdgcn_sinf(xv);
        float c1  = __builtin_amdgcn_cosf(xv);
        float w16 = __builtin_amdgcn_fractf(16.f * xv);   // 16x exact in f32
        float s16 = __builtin_amdgcn_sinf(w16);
        float c16 = __builtin_amdgcn_cosf(w16);
        const float c2x = 2.f * c1;
        float sA0 = 0.f,  sA1 = s1;                        // sin(2pi*w*x)
        float sB0 = s16,  sB1 = fmaf(s16, c1, c16 * s1);   // sin(2pi*(16+w)*x)
        float res = 0.f;
        const unsigned int* Tr = Tw + lane * TSTRIDE;
#pragma unroll
        for (int w = 0; w < 16; ++w) {
            f16x2 h = __builtin_bit_cast(f16x2, Tr[w]);
            res = fmaf(sA0, (float)h[0], res);
            res = fmaf(sB0, (float)h[1], res);   // i>=24: T==0
            float nA = fmaf(c2x, sA1, -sA0);
            float nB = fmaf(c2x, sB1, -sB0);
            sA0 = sA1; sA1 = nA;
            sB0 = sB1; sB1 = nB;
        }
        out[p] = res;
    }
}

extern "C" void kernel_launch(void* const* d_in, const int* in_sizes, int n_in,
                              void* d_out, int out_size, void* d_ws, size_t ws_size,
                              hipStream_t stream) {
    const float* xyz    = (const float*)d_in[0];
    const float* coeffs = (const float*)d_in[1];
    float* out = (float*)d_out;
    f16x8* wsB = (f16x8*)d_ws;                 // needs 36864 B

    prep_B<<<9, 256, 0, stream>>>(coeffs, wsB);

    const int n = in_sizes[0] / 3;             // 524288 = 1024 blocks * 8 waves * 64
    const int grid = n / 512;
    fourier_main<<<grid, 512, 0, stream>>>(xyz, wsB, out);
}